// Round 6
// baseline (565.840 us; speedup 1.0000x reference)
//
#include <hip/hip_runtime.h>
#include <hip/hip_bf16.h>

// CLIP loss: B=8192, D=1024, temp=0.5.
// loss = mean_i [ 0.5*(log sum_j exp(s_ij) + log sum_j exp(s_ji)) - s_ii ],
// s = (zi_n @ zj_n^T) * 2.  |s| <= 2 -> exp safe, no max trick.
//
// R6: MX-fp8 GEMM. Inputs normalized+cast to fp8 e4m3 (OCP). MFMA =
// mfma_scale_f32_32x32x64_f8f6f4 with unit scales (0x7F bytes) -> 2x bf16
// rate, and fp8 halves LDS reads/writes + staging bytes.
// Tile 256x256, BK=64, 8 waves (2M x 4N), per-wave 128x64 = 4x2 frags of
// 32x32 (acc f32x16[8] = 128 VGPR). Ring-3 LDS buffers (96 KB), counted
// vmcnt(8), 2 barriers/tile. 16B-chunk swizzle cphys = c ^ ((row>>1)&3)
// both sides (stage source pre-swizzled, ds_read swizzled) -> perfectly
// packed b128 reads (8 words/bank).
//
// ws: [0,8M) zi8 (x2 temp folded), [8M,16M) zj8, [16M,+1M) rp[32][8192],
//     [17M,+1M) cp[32][8192], [18M,+32K) dg[8192], then part[32].

using f32x16 = __attribute__((ext_vector_type(16))) float;
using i32x8  = __attribute__((ext_vector_type(8))) int;
using i32x4  = __attribute__((ext_vector_type(4))) int;

#define USCL 0x7F7F7F7Fu   // E8M0 = 127 -> scale 1.0 in every byte

__device__ __forceinline__ void async16(const unsigned char* g, unsigned char* l) {
    __builtin_amdgcn_global_load_lds(
        (const __attribute__((address_space(1))) void*)g,
        (__attribute__((address_space(3))) void*)l, 16, 0, 0);
}

// ---- kernel 1: row-normalize fp32 -> fp8 e4m3, extra scale folded ----
__global__ __launch_bounds__(256) void clip_norm_k(const float* __restrict__ in,
                                                   unsigned int* __restrict__ out,
                                                   float extra) {
    int row = blockIdx.x;
    const float4* ip = reinterpret_cast<const float4*>(in + (size_t)row * 1024);
    float4 v = ip[threadIdx.x];
    float ss = v.x * v.x + v.y * v.y + v.z * v.z + v.w * v.w;
    #pragma unroll
    for (int o = 1; o < 64; o <<= 1) ss += __shfl_xor(ss, o);
    __shared__ float sb[4];
    if ((threadIdx.x & 63) == 0) sb[threadIdx.x >> 6] = ss;
    __syncthreads();
    float tot = sb[0] + sb[1] + sb[2] + sb[3];
    float scl = extra / fmaxf(sqrtf(tot), 1e-12f);
    int p = __builtin_amdgcn_cvt_pk_fp8_f32(v.x * scl, v.y * scl, 0, false);
    p = __builtin_amdgcn_cvt_pk_fp8_f32(v.z * scl, v.w * scl, p, true);
    out[(size_t)row * 256 + threadIdx.x] = (unsigned int)p;
}

// Stage one [256 rows][64 B] fp8 tile (16 KB): 2 sweeps x 512 thr x 16B.
// Linear LDS dest; source pre-swizzled with the read involution.
__device__ __forceinline__ void stage_tile(const unsigned char* G,
                                           unsigned char* buf,
                                           int ktB, int tid) {
    #pragma unroll
    for (int s = 0; s < 2; ++s) {
        int idx = s * 512 + tid;
        int row = idx >> 2;
        int clog = (idx & 3) ^ ((row >> 1) & 3);
        async16(G + (size_t)row * 1024 + ktB + clog * 16, buf + idx * 16);
    }
}

// Read a 32B fp8 fragment (row = l&31 within frag, k-half h = l>>5).
__device__ __forceinline__ i32x8 ldfrag(const unsigned char* buf, int row, int h) {
    int c0 = (2 * h) ^ ((row >> 1) & 3);
    i32x4 lo = *reinterpret_cast<const i32x4*>(buf + row * 64 + c0 * 16);
    i32x4 hi = *reinterpret_cast<const i32x4*>(buf + row * 64 + (c0 ^ 1) * 16);
    i32x8 r;
    r[0] = lo[0]; r[1] = lo[1]; r[2] = lo[2]; r[3] = lo[3];
    r[4] = hi[0]; r[5] = hi[1]; r[6] = hi[2]; r[7] = hi[3];
    return r;
}

__global__ __launch_bounds__(512, 2) void clip_gemm_k(
    const unsigned char* __restrict__ A,   // zi8 [8192][1024]
    const unsigned char* __restrict__ Bm,  // zj8 [8192][1024]
    float* __restrict__ rp, float* __restrict__ cp, float* __restrict__ dg) {
    __shared__ unsigned char tile[3 * 32768];   // ring-3: each {A 16K, B 16K}
    __shared__ float rbuf[4][256];
    __shared__ float cbuf[2][256];

    // XCD stripe swizzle: 1024 blocks, XCD c gets bj in [4c,4c+4), all bi.
    const int c_x = blockIdx.x & 7, q = blockIdx.x >> 3;
    const int bj = c_x * 4 + (q & 3);        // 0..31
    const int bi = q >> 2;                   // 0..31
    const int tid = threadIdx.x;
    const int l = tid & 63, w = tid >> 6;
    const int wm = w >> 2, wn = w & 3;       // 2M x 4N wave grid
    const int lane31 = l & 31, h = l >> 5;

    f32x16 acc[8] = {};                      // [fm*2+fn], fm 0..3, fn 0..1

    const unsigned char* Ag = A + (size_t)(bi * 256) * 1024;
    const unsigned char* Bg = Bm + (size_t)(bj * 256) * 1024;

    unsigned char* bA0 = tile;               unsigned char* bB0 = tile + 16384;
    unsigned char* bA1 = tile + 32768;       unsigned char* bB1 = tile + 49152;
    unsigned char* bA2 = tile + 65536;       unsigned char* bB2 = tile + 81920;

    // prologue: stage tiles 0,1,2
    stage_tile(Ag, bA0, 0, tid);
    stage_tile(Bg, bB0, 0, tid);
    stage_tile(Ag, bA1, 64, tid);
    stage_tile(Bg, bB1, 64, tid);
    stage_tile(Ag, bA2, 128, tid);
    stage_tile(Bg, bB2, 128, tid);
    asm volatile("s_waitcnt vmcnt(8)" ::: "memory");   // tile 0 landed
    __builtin_amdgcn_s_barrier();
    __builtin_amdgcn_sched_barrier(0);

    for (int t = 0; t < 16; ++t) {
        // ---- compute tile t from (bA0,bB0) ----
        i32x8 af[4], bfr[2];
        #pragma unroll
        for (int m = 0; m < 4; ++m)
            af[m] = ldfrag(bA0, wm * 128 + m * 32 + lane31, h);
        #pragma unroll
        for (int n = 0; n < 2; ++n)
            bfr[n] = ldfrag(bB0, wn * 64 + n * 32 + lane31, h);
        #pragma unroll
        for (int m = 0; m < 4; ++m)
            #pragma unroll
            for (int n = 0; n < 2; ++n)
                acc[m * 2 + n] = __builtin_amdgcn_mfma_scale_f32_32x32x64_f8f6f4(
                    af[m], bfr[n], acc[m * 2 + n], 0, 0, 0, USCL, 0, USCL);

        asm volatile("s_waitcnt lgkmcnt(0)" ::: "memory");
        __builtin_amdgcn_s_barrier();        // all waves done reading buf0
        if (t <= 12) {
            stage_tile(Ag, bA0, (t + 3) * 64, tid);   // restage freed buffer
            stage_tile(Bg, bB0, (t + 3) * 64, tid);
            asm volatile("s_waitcnt vmcnt(8)" ::: "memory");   // t+1 landed
        } else if (t == 13) {
            asm volatile("s_waitcnt vmcnt(4)" ::: "memory");   // t=14 landed
        } else if (t == 14) {
            asm volatile("s_waitcnt vmcnt(0)" ::: "memory");   // t=15 landed
        }
        if (t <= 14) {
            __builtin_amdgcn_s_barrier();
            __builtin_amdgcn_sched_barrier(0);
        }
        // rotate ring
        unsigned char* tp;
        tp = bA0; bA0 = bA1; bA1 = bA2; bA2 = tp;
        tp = bB0; bB0 = bB1; bB1 = bB2; bB2 = tp;
    }

    // ---- epilogue ----
    // 32x32 C/D layout: col = l&31, row = (reg&3) + 8*(reg>>2) + 4*(l>>5).
    if (bi == bj) {
        #pragma unroll
        for (int fm = 0; fm < 4; ++fm)
            #pragma unroll
            for (int fn = 0; fn < 2; ++fn)
                #pragma unroll
                for (int reg = 0; reg < 16; ++reg) {
                    int rif = (reg & 3) + 8 * (reg >> 2) + 4 * h;
                    int lrow = wm * 128 + fm * 32 + rif;
                    int lcol = wn * 64 + fn * 32 + lane31;
                    if (lrow == lcol) dg[bi * 256 + lrow] = acc[fm * 2 + fn][reg];
                }
    }

    #pragma unroll
    for (int f = 0; f < 8; ++f)
        #pragma unroll
        for (int reg = 0; reg < 16; ++reg)
            acc[f][reg] = exp2f(acc[f][reg] * 1.44269504f);

    // row sums: combine fn in-reg, butterfly over the 32-lane half
    #pragma unroll
    for (int fm = 0; fm < 4; ++fm) {
        #pragma unroll
        for (int reg = 0; reg < 16; ++reg) {
            float v = acc[fm * 2][reg] + acc[fm * 2 + 1][reg];
            v += __shfl_xor(v, 1);
            v += __shfl_xor(v, 2);
            v += __shfl_xor(v, 4);
            v += __shfl_xor(v, 8);
            v += __shfl_xor(v, 16);
            if (lane31 == 0) {
                int rif = (reg & 3) + 8 * (reg >> 2) + 4 * h;
                rbuf[wn][wm * 128 + fm * 32 + rif] = v;
            }
        }
    }
    // col sums: sum regs+fm in-lane, swap halves
    #pragma unroll
    for (int fn = 0; fn < 2; ++fn) {
        float v = 0.f;
        #pragma unroll
        for (int fm = 0; fm < 4; ++fm)
            #pragma unroll
            for (int reg = 0; reg < 16; ++reg)
                v += acc[fm * 2 + fn][reg];
        v += __shfl_xor(v, 32);
        if (h == 0) cbuf[wm][wn * 64 + fn * 32 + lane31] = v;
    }
    __syncthreads();
    if (tid < 256) {
        rp[(size_t)bj * 8192 + bi * 256 + tid] =
            rbuf[0][tid] + rbuf[1][tid] + rbuf[2][tid] + rbuf[3][tid];
        cp[(size_t)bi * 8192 + bj * 256 + tid] = cbuf[0][tid] + cbuf[1][tid];
    }
}

// ---- per-row logs, block partial sums ----
__global__ __launch_bounds__(256) void clip_fin1_k(const float* __restrict__ rp,
                                                   const float* __restrict__ cp,
                                                   const float* __restrict__ dg,
                                                   float* __restrict__ part) {
    int i = blockIdx.x * 256 + threadIdx.x;
    float rs = 0.f, cs = 0.f;
    #pragma unroll 8
    for (int b = 0; b < 32; ++b) rs += rp[(size_t)b * 8192 + i];
    #pragma unroll 8
    for (int b = 0; b < 32; ++b) cs += cp[(size_t)b * 8192 + i];
    float c = 0.5f * (logf(rs) + logf(cs)) - dg[i];
    #pragma unroll
    for (int o = 1; o < 64; o <<= 1) c += __shfl_xor(c, o);
    __shared__ float sb[4];
    if ((threadIdx.x & 63) == 0) sb[threadIdx.x >> 6] = c;
    __syncthreads();
    if (threadIdx.x == 0) part[blockIdx.x] = sb[0] + sb[1] + sb[2] + sb[3];
}

__global__ void clip_fin2_k(const float* __restrict__ part, float* __restrict__ out) {
    float v = (threadIdx.x < 32) ? part[threadIdx.x] : 0.f;
    #pragma unroll
    for (int o = 1; o < 64; o <<= 1) v += __shfl_xor(v, o);
    if (threadIdx.x == 0) out[0] = v * (1.f / 8192.f);
}

extern "C" void kernel_launch(void* const* d_in, const int* in_sizes, int n_in,
                              void* d_out, int out_size, void* d_ws, size_t ws_size,
                              hipStream_t stream) {
    const float* zi = (const float*)d_in[0];
    const float* zj = (const float*)d_in[1];
    float* out = (float*)d_out;
    char* ws = (char*)d_ws;

    unsigned int* zi8 = (unsigned int*)(ws);
    unsigned int* zj8 = (unsigned int*)(ws + (size_t)8 * 1024 * 1024);
    float* rp   = (float*)(ws + (size_t)16 * 1024 * 1024);
    float* cp   = (float*)(ws + (size_t)17 * 1024 * 1024);
    float* dg   = (float*)(ws + (size_t)18 * 1024 * 1024);
    float* part = (float*)(ws + (size_t)18 * 1024 * 1024 + 32768);

    clip_norm_k<<<8192, 256, 0, stream>>>(zi, zi8, 2.0f);   // temp x2 folded into zi
    clip_norm_k<<<8192, 256, 0, stream>>>(zj, zj8, 1.0f);
    clip_gemm_k<<<1024, 512, 0, stream>>>((const unsigned char*)zi8,
                                          (const unsigned char*)zj8, rp, cp, dg);
    clip_fin1_k<<<32, 256, 0, stream>>>(rp, cp, dg, part);
    clip_fin2_k<<<1, 64, 0, stream>>>(part, out);
}